// Round 1
// baseline (95.381 us; speedup 1.0000x reference)
//
#include <hip/hip_runtime.h>
#include <hip/hip_bf16.h>

#define N 8192
#define D 128
#define HALF_N 4096
#define SCALE 10.0f  // 1/TEMPERATURE

#define BLOCK_ROWS 256   // 4 waves * 64 rows each
#define COLS_PER_ITER 64
#define COL_SPLITS 16
#define COLS_PER_BLOCK (N / COL_SPLITS)          // 512
#define ITERS (COLS_PER_BLOCK / COLS_PER_ITER)   // 8
#define LDS_STRIDE 136   // 128 + 8 pad: row advances 4 banks -> 2-way (free)

typedef short frag8 __attribute__((ext_vector_type(8)));
typedef float f32x4 __attribute__((ext_vector_type(4)));

__device__ __forceinline__ unsigned short f2bf(float f) {
    unsigned int u = __float_as_uint(f);
    u += 0x7FFFu + ((u >> 16) & 1u);
    return (unsigned short)(u >> 16);
}

// K1: normalize each row to unit length (eps-clamped), emit bf16 z; zero accumulators.
__global__ __launch_bounds__(64) void k_normalize(const float* __restrict__ x,
                                                  unsigned short* __restrict__ z,
                                                  float* __restrict__ sumexp,
                                                  float* __restrict__ pos) {
    const int row = blockIdx.x;
    const int lane = threadIdx.x;
    float2 v = ((const float2*)x)[row * 64 + lane];
    float s = v.x * v.x + v.y * v.y;
    #pragma unroll
    for (int m = 32; m >= 1; m >>= 1) s += __shfl_xor(s, m);
    float norm = fmaxf(sqrtf(s), 1e-8f);
    float inv = 1.0f / norm;
    ushort2 o;
    o.x = f2bf(v.x * inv);
    o.y = f2bf(v.y * inv);
    ((ushort2*)z)[row * 64 + lane] = o;
    if (lane == 0) sumexp[row] = 0.0f;
    if (lane == 1) pos[row] = 0.0f;
}

// K2: fused z.z^T GEMM + exp + per-row partial sums; capture pos entries.
__global__ __launch_bounds__(256, 2) void k_simloss(const unsigned short* __restrict__ z,
                                                    float* __restrict__ sumexp,
                                                    float* __restrict__ pos) {
    __shared__ unsigned short lds[COLS_PER_ITER * LDS_STRIDE];  // 17408 B

    const int tid  = threadIdx.x;
    const int wave = tid >> 6;
    const int lane = tid & 63;
    const int l15  = lane & 15;
    const int quad = lane >> 4;
    const int wrow = blockIdx.x * BLOCK_ROWS + wave * 64;  // this wave's 64 rows
    const int colbase0 = blockIdx.y * COLS_PER_BLOCK;

    // A fragments: 4 row-stripes of 16 x full K=128 (4 chunks of 32), register-resident.
    // A layout (16x16x32): lane holds A[m=lane&15][k=quad*8+j], j=0..7 -> 16B contiguous.
    frag8 a[4][4];
    #pragma unroll
    for (int s = 0; s < 4; ++s) {
        const uint4* p = (const uint4*)&z[(wrow + s * 16 + l15) * D + quad * 8];
        #pragma unroll
        for (int q = 0; q < 4; ++q) {
            uint4 t = p[q * 4];  // q*32 ushorts = q*4 uint4
            a[s][q] = *(frag8*)&t;
        }
    }

    float sums[4][4];
    #pragma unroll
    for (int s = 0; s < 4; ++s)
        #pragma unroll
        for (int r = 0; r < 4; ++r) sums[s][r] = 0.0f;

    for (int it = 0; it < ITERS; ++it) {
        const int colbase = colbase0 + it * COLS_PER_ITER;
        __syncthreads();
        // Stage 64 cols x 128 K bf16 tile (16 KB) cooperatively, padded stride.
        #pragma unroll
        for (int u = 0; u < 4; ++u) {
            int idx = u * 256 + tid;        // 1024 units of 8 bf16
            int r   = idx >> 4;             // 16 units per row
            int c8  = idx & 15;
            uint4 t = *(const uint4*)&z[(colbase + r) * D + c8 * 8];
            *(uint4*)&lds[r * LDS_STRIDE + c8 * 8] = t;
        }
        __syncthreads();

        const unsigned short* lp = &lds[l15 * LDS_STRIDE + quad * 8];
        #pragma unroll
        for (int c = 0; c < 4; ++c) {
            f32x4 acc[4];
            #pragma unroll
            for (int s = 0; s < 4; ++s) acc[s] = (f32x4){0.f, 0.f, 0.f, 0.f};
            #pragma unroll
            for (int q = 0; q < 4; ++q) {
                // B layout mirrors A: lane holds B[n=lane&15][k=quad*8+j]
                frag8 b = *(const frag8*)(lp + c * 16 * LDS_STRIDE + q * 32);
                #pragma unroll
                for (int s = 0; s < 4; ++s)
                    acc[s] = __builtin_amdgcn_mfma_f32_16x16x32_bf16(a[s][q], b, acc[s], 0, 0, 0);
            }
            const int gcol = colbase + c * 16 + l15;
            #pragma unroll
            for (int s = 0; s < 4; ++s) {
                const int growb = wrow + s * 16 + quad * 4;  // C: row=(lane>>4)*4+reg, col=lane&15
                #pragma unroll
                for (int r = 0; r < 4; ++r) {
                    const int grow = growb + r;
                    float val = acc[s][r] * SCALE;
                    float e = __expf(val);
                    if (gcol == grow) e = 0.0f;           // diag masked (exp(-9e15)=0)
                    sums[s][r] += e;
                    if (gcol == ((grow + HALF_N) & (N - 1))) pos[grow] = val;
                }
            }
        }
    }

    // Reduce each row-sum across the 16 lanes (same quad group) holding that row.
    #pragma unroll
    for (int s = 0; s < 4; ++s) {
        #pragma unroll
        for (int r = 0; r < 4; ++r) {
            float v = sums[s][r];
            v += __shfl_xor(v, 1);
            v += __shfl_xor(v, 2);
            v += __shfl_xor(v, 4);
            v += __shfl_xor(v, 8);
            if (l15 == 0) atomicAdd(&sumexp[wrow + s * 16 + quad * 4 + r], v);
        }
    }
}

// K3: loss_i = log(sumexp_i) - pos_i ; output mean.
__global__ __launch_bounds__(256) void k_finalize(const float* __restrict__ sumexp,
                                                  const float* __restrict__ pos,
                                                  float* __restrict__ out) {
    const int tid = threadIdx.x;
    float acc = 0.0f;
    for (int i = tid; i < N; i += 256)
        acc += logf(sumexp[i]) - pos[i];
    #pragma unroll
    for (int m = 32; m >= 1; m >>= 1) acc += __shfl_xor(acc, m);
    __shared__ float partial[4];
    if ((tid & 63) == 0) partial[tid >> 6] = acc;
    __syncthreads();
    if (tid == 0)
        out[0] = (partial[0] + partial[1] + partial[2] + partial[3]) * (1.0f / N);
}

extern "C" void kernel_launch(void* const* d_in, const int* in_sizes, int n_in,
                              void* d_out, int out_size, void* d_ws, size_t ws_size,
                              hipStream_t stream) {
    const float* x = (const float*)d_in[0];
    float* sumexp = (float*)d_ws;                                   // N floats
    float* pos    = sumexp + N;                                     // N floats
    unsigned short* z = (unsigned short*)((char*)d_ws + 2 * N * 4); // N*D bf16 (offset 64 KB)

    k_normalize<<<N, 64, 0, stream>>>(x, z, sumexp, pos);
    dim3 g2(N / BLOCK_ROWS, COL_SPLITS);  // (32, 16) = 512 blocks
    k_simloss<<<g2, 256, 0, stream>>>(z, sumexp, pos);
    k_finalize<<<1, 256, 0, stream>>>(sumexp, pos, (float*)d_out);
}